// Round 1
// baseline (417.139 us; speedup 1.0000x reference)
//
#include <hip/hip_runtime.h>
#include <math.h>

// ---------------------------------------------------------------------------
// WCSA: channel attention (per-head 64x64 over K=2048) + spatial attention
// (per-head 2048x2048, d=64, d_s=16) with "raw reshape" head semantics:
// head hh of batch b = contiguous slice of the (N,C) projection at
// offset b*N*C + hh*N*d, viewed as (N,d) row-major.
// Round 1: all-f32 correctness baseline.
// ---------------------------------------------------------------------------

constexpr int Bb = 4, Nn = 2048, Hh = 4;
constexpr int PROJ_B = Nn * 256;   // 524288 floats per batch for 256-col projections
constexpr int HEAD_C = Nn * 64;    // 131072 floats per (b,h) head slice (d=64)
constexpr int HEAD_S = Nn * 16;    // 32768 floats per (b,h) head slice (d_s=16)

// workspace layout (floats)
constexpr size_t OFF_QC   = 0;
constexpr size_t OFF_QS   = OFF_QC + (size_t)Bb * PROJ_B;
constexpr size_t OFF_KC   = OFF_QS + (size_t)Bb * PROJ_B;
constexpr size_t OFF_VC   = OFF_KC + (size_t)Bb * PROJ_B;
constexpr size_t OFF_KS   = OFF_VC + (size_t)Bb * PROJ_B;
constexpr size_t OFF_VS   = OFF_KS + (size_t)Bb * PROJ_B;          // B*N*64
constexpr size_t OFF_PART = OFF_VS + (size_t)Bb * Nn * 64;         // 16*8*4096
constexpr size_t OFF_SCA  = OFF_PART + (size_t)16 * 8 * 4096;      // 16*4096

// ---------------------------------------------------------------------------
// C[M,N] = X[M,K] @ W[N,K]^T   (Linear without bias). 64x64 tile, BK=32.
// ---------------------------------------------------------------------------
__global__ __launch_bounds__(256) void gemm_xwt(const float* __restrict__ X,
                                                const float* __restrict__ W,
                                                float* __restrict__ C,
                                                int M, int N, int K)
{
    __shared__ float Xs[32][68];   // [k][m], pad 68 (16B-aligned rows, stride 4 banks)
    __shared__ float Ws[32][68];   // [k][n]
    const int t = threadIdx.x;
    const int ty = t >> 4, tx = t & 15;
    const int m0 = blockIdx.y * 64, n0 = blockIdx.x * 64;

    float acc[4][4] = {};
    for (int k0 = 0; k0 < K; k0 += 32) {
        __syncthreads();
        #pragma unroll
        for (int q = t; q < 512; q += 256) {          // 64 rows x 8 float4
            int row = q >> 3, c4 = q & 7;
            float4 f = *(const float4*)&X[(size_t)(m0 + row) * K + k0 + c4 * 4];
            Xs[c4 * 4 + 0][row] = f.x; Xs[c4 * 4 + 1][row] = f.y;
            Xs[c4 * 4 + 2][row] = f.z; Xs[c4 * 4 + 3][row] = f.w;
            float4 g = *(const float4*)&W[(size_t)(n0 + row) * K + k0 + c4 * 4];
            Ws[c4 * 4 + 0][row] = g.x; Ws[c4 * 4 + 1][row] = g.y;
            Ws[c4 * 4 + 2][row] = g.z; Ws[c4 * 4 + 3][row] = g.w;
        }
        __syncthreads();
        #pragma unroll 8
        for (int kk = 0; kk < 32; ++kk) {
            float4 x4 = *(const float4*)&Xs[kk][ty * 4];
            float4 w4 = *(const float4*)&Ws[kk][tx * 4];
            float xa[4] = {x4.x, x4.y, x4.z, x4.w};
            float wa[4] = {w4.x, w4.y, w4.z, w4.w};
            #pragma unroll
            for (int ii = 0; ii < 4; ++ii)
                #pragma unroll
                for (int jj = 0; jj < 4; ++jj)
                    acc[ii][jj] += xa[ii] * wa[jj];
        }
    }
    #pragma unroll
    for (int ii = 0; ii < 4; ++ii) {
        float4 r = make_float4(acc[ii][0], acc[ii][1], acc[ii][2], acc[ii][3]);
        *(float4*)&C[(size_t)(m0 + ty * 4 + ii) * N + n0 + tx * 4] = r;
    }
}

// ---------------------------------------------------------------------------
// Channel branch stage 1: partial S[i,j] = sum_n Qc[n,i]*Kc[n,j] over a 256-row
// chunk. grid = (chunk=8, h=4, b=4). part[((b*4+h)*8+ch)*4096 + i*64 + j].
// ---------------------------------------------------------------------------
__global__ __launch_bounds__(256) void chan_qk_partial(const float* __restrict__ Pqc,
                                                       const float* __restrict__ Pkc,
                                                       float* __restrict__ part)
{
    const int ch = blockIdx.x, hh = blockIdx.y, b = blockIdx.z;
    const float* Q = Pqc + (size_t)b * PROJ_B + (size_t)hh * HEAD_C;  // (2048,64)
    const float* Kk = Pkc + (size_t)b * PROJ_B + (size_t)hh * HEAD_C;
    __shared__ float Qs[64][68], Ks[64][68];   // [n_local][chan]
    const int t = threadIdx.x, ty = t >> 4, tx = t & 15;

    float acc[4][4] = {};
    for (int sub = 0; sub < 4; ++sub) {
        const int r0 = ch * 256 + sub * 64;
        __syncthreads();
        #pragma unroll
        for (int q = t; q < 1024; q += 256) {   // 64 rows x 16 float4
            int row = q >> 4, c4 = q & 15;
            *(float4*)&Qs[row][c4 * 4] = *(const float4*)&Q[(size_t)(r0 + row) * 64 + c4 * 4];
            *(float4*)&Ks[row][c4 * 4] = *(const float4*)&Kk[(size_t)(r0 + row) * 64 + c4 * 4];
        }
        __syncthreads();
        #pragma unroll 8
        for (int nn = 0; nn < 64; ++nn) {
            float4 q4 = *(const float4*)&Qs[nn][ty * 4];
            float4 k4 = *(const float4*)&Ks[nn][tx * 4];
            float qa[4] = {q4.x, q4.y, q4.z, q4.w};
            float ka[4] = {k4.x, k4.y, k4.z, k4.w};
            #pragma unroll
            for (int ii = 0; ii < 4; ++ii)
                #pragma unroll
                for (int jj = 0; jj < 4; ++jj)
                    acc[ii][jj] += qa[ii] * ka[jj];
        }
    }
    float* P = part + (((size_t)(b * 4 + hh) * 8 + ch) << 12);
    #pragma unroll
    for (int ii = 0; ii < 4; ++ii) {
        float4 r = make_float4(acc[ii][0], acc[ii][1], acc[ii][2], acc[ii][3]);
        *(float4*)&P[(ty * 4 + ii) * 64 + tx * 4] = r;
    }
}

// ---------------------------------------------------------------------------
// Channel branch stage 2: reduce 8 partials, scale by (1/8)*temp[h], softmax
// rows -> Sca[(b*4+h)*4096 + i*64 + j]. grid = 16 blocks x 64 threads.
// ---------------------------------------------------------------------------
__global__ __launch_bounds__(64) void chan_softmax(const float* __restrict__ part,
                                                   const float* __restrict__ temp,
                                                   float* __restrict__ Sca)
{
    const int bh = blockIdx.x;
    const int h = bh & 3;
    const int i = threadIdx.x;          // row
    __shared__ float Ss[64][65];
    const float sT = 0.125f * temp[h];

    float m = -1e30f;
    for (int j = 0; j < 64; ++j) {
        float v = 0.f;
        #pragma unroll
        for (int c = 0; c < 8; ++c)
            v += part[((size_t)bh * 8 + c) * 4096 + i * 64 + j];
        v *= sT;
        Ss[i][j] = v;
        m = fmaxf(m, v);
    }
    float sum = 0.f;
    for (int j = 0; j < 64; ++j) {
        float p = __expf(Ss[i][j] - m);
        Ss[i][j] = p;
        sum += p;
    }
    const float inv = 1.0f / sum;
    for (int j = 0; j < 64; ++j)
        Sca[((size_t)bh << 12) + i * 64 + j] = Ss[i][j] * inv;
}

// ---------------------------------------------------------------------------
// Channel branch stage 3: x_ca[dr,nn] = sum_d S[dr,d] * Vc[nn,d], scattered to
// out[b, n, cc] with n = rem>>8, cc = rem&255, rem = hh*131072 + dr*2048 + nn.
// grid = (nchunk=8, h=4, b=4); thread owns one nn.
// ---------------------------------------------------------------------------
__global__ __launch_bounds__(256) void chan_out(const float* __restrict__ Sca,
                                                const float* __restrict__ Pvc,
                                                float* __restrict__ out)
{
    const int nc = blockIdx.x, hh = blockIdx.y, b = blockIdx.z;
    __shared__ float Ss[64][68];
    const int t = threadIdx.x;
    const float* S = Sca + ((size_t)(b * 4 + hh) << 12);
    #pragma unroll
    for (int q = t; q < 1024; q += 256) {
        int dr = q >> 4, c4 = q & 15;
        *(float4*)&Ss[dr][c4 * 4] = *(const float4*)&S[dr * 64 + c4 * 4];
    }
    __syncthreads();

    const float* V = Pvc + (size_t)b * PROJ_B + (size_t)hh * HEAD_C;
    const int nn = nc * 256 + t;
    float v[64];
    const float4* vp = (const float4*)&V[(size_t)nn * 64];
    #pragma unroll
    for (int q = 0; q < 16; ++q) {
        float4 f = vp[q];
        v[q * 4] = f.x; v[q * 4 + 1] = f.y; v[q * 4 + 2] = f.z; v[q * 4 + 3] = f.w;
    }
    float* ob = out + (size_t)b * (Nn * 320);
    #pragma unroll 4
    for (int dr = 0; dr < 64; ++dr) {
        float a = 0.f;
        #pragma unroll
        for (int d4 = 0; d4 < 16; ++d4) {
            float4 s4 = *(const float4*)&Ss[dr][d4 * 4];
            a += s4.x * v[d4 * 4] + s4.y * v[d4 * 4 + 1]
               + s4.z * v[d4 * 4 + 2] + s4.w * v[d4 * 4 + 3];
        }
        int rem = hh * 131072 + dr * 2048 + nn;
        ob[(rem >> 8) * 320 + (rem & 255)] = a;
    }
}

// ---------------------------------------------------------------------------
// Spatial branch: flash attention per (b,h): Q,K (2048,64), V (2048,16).
// Block = 64 query rows; iterate 32 chunks of 64 keys. 16x16 thread layout,
// 4x4 micro-tile; row softmax via __shfl_xor within 16-lane groups.
// Output O[nn,dd] -> out[b, hh*512 + nn/4, 256 + (nn%4)*16 + dd].
// ---------------------------------------------------------------------------
__global__ __launch_bounds__(256) void spatial_attn(const float* __restrict__ Pqs,
                                                    const float* __restrict__ Pks,
                                                    const float* __restrict__ Pvs,
                                                    const float* __restrict__ temp2,
                                                    float* __restrict__ out)
{
    const int rt = blockIdx.x, hh = blockIdx.y, b = blockIdx.z;
    const int t = threadIdx.x, ty = t >> 4, tx = t & 15;
    __shared__ float Qs[64][68];   // [k][row]   (transposed)
    __shared__ float Ks[64][68];   // [k][col]   (transposed)
    __shared__ float Vs[64][20];   // [col][dd]
    __shared__ float Ob[64][16];

    const float* Q = Pqs + (size_t)b * PROJ_B + (size_t)hh * HEAD_C;
    const float* K = Pks + (size_t)b * PROJ_B + (size_t)hh * HEAD_C;
    const float* V = Pvs + (size_t)b * (Nn * 64) + (size_t)hh * HEAD_S;
    const float sT = 0.125f * temp2[hh];

    // stage Q tile transposed
    #pragma unroll
    for (int q = t; q < 1024; q += 256) {
        int row = q >> 4, c4 = q & 15;
        float4 f = *(const float4*)&Q[(size_t)(rt * 64 + row) * 64 + c4 * 4];
        Qs[c4 * 4 + 0][row] = f.x; Qs[c4 * 4 + 1][row] = f.y;
        Qs[c4 * 4 + 2][row] = f.z; Qs[c4 * 4 + 3][row] = f.w;
    }

    float m[4], l[4], o[4][16];
    #pragma unroll
    for (int i = 0; i < 4; ++i) {
        m[i] = -1e30f; l[i] = 0.f;
        #pragma unroll
        for (int dd = 0; dd < 16; ++dd) o[i][dd] = 0.f;
    }

    for (int kc = 0; kc < 32; ++kc) {
        __syncthreads();
        #pragma unroll
        for (int q = t; q < 1024; q += 256) {
            int row = q >> 4, c4 = q & 15;
            float4 f = *(const float4*)&K[(size_t)(kc * 64 + row) * 64 + c4 * 4];
            Ks[c4 * 4 + 0][row] = f.x; Ks[c4 * 4 + 1][row] = f.y;
            Ks[c4 * 4 + 2][row] = f.z; Ks[c4 * 4 + 3][row] = f.w;
        }
        #pragma unroll
        for (int q = t; q < 256; q += 256) {
            int row = q >> 2, c4 = q & 3;
            *(float4*)&Vs[row][c4 * 4] = *(const float4*)&V[(size_t)(kc * 64 + row) * 16 + c4 * 4];
        }
        __syncthreads();

        // S = Q K^T for this tile, 4x4 per thread
        float s[4][4] = {};
        #pragma unroll 8
        for (int k = 0; k < 64; ++k) {
            float4 q4 = *(const float4*)&Qs[k][ty * 4];
            float4 k4 = *(const float4*)&Ks[k][tx * 4];
            float qa[4] = {q4.x, q4.y, q4.z, q4.w};
            float ka[4] = {k4.x, k4.y, k4.z, k4.w};
            #pragma unroll
            for (int i = 0; i < 4; ++i)
                #pragma unroll
                for (int j = 0; j < 4; ++j)
                    s[i][j] += qa[i] * ka[j];
        }

        // online softmax per row (16-lane groups share a row set)
        #pragma unroll
        for (int i = 0; i < 4; ++i) {
            #pragma unroll
            for (int j = 0; j < 4; ++j) s[i][j] *= sT;
            float cm = fmaxf(fmaxf(s[i][0], s[i][1]), fmaxf(s[i][2], s[i][3]));
            cm = fmaxf(cm, __shfl_xor(cm, 1, 16));
            cm = fmaxf(cm, __shfl_xor(cm, 2, 16));
            cm = fmaxf(cm, __shfl_xor(cm, 4, 16));
            cm = fmaxf(cm, __shfl_xor(cm, 8, 16));
            float mn = fmaxf(m[i], cm);
            float corr = __expf(m[i] - mn);
            float ps = 0.f;
            #pragma unroll
            for (int j = 0; j < 4; ++j) { s[i][j] = __expf(s[i][j] - mn); ps += s[i][j]; }
            ps += __shfl_xor(ps, 1, 16);
            ps += __shfl_xor(ps, 2, 16);
            ps += __shfl_xor(ps, 4, 16);
            ps += __shfl_xor(ps, 8, 16);
            l[i] = l[i] * corr + ps;
            m[i] = mn;
            #pragma unroll
            for (int dd = 0; dd < 16; ++dd) o[i][dd] *= corr;
        }

        // O += P @ V (this thread's 4 key-columns)
        #pragma unroll
        for (int j = 0; j < 4; ++j) {
            const float* vr = &Vs[tx * 4 + j][0];
            float4 v0 = *(const float4*)&vr[0];
            float4 v1 = *(const float4*)&vr[4];
            float4 v2 = *(const float4*)&vr[8];
            float4 v3 = *(const float4*)&vr[12];
            float va[16] = {v0.x, v0.y, v0.z, v0.w, v1.x, v1.y, v1.z, v1.w,
                            v2.x, v2.y, v2.z, v2.w, v3.x, v3.y, v3.z, v3.w};
            #pragma unroll
            for (int i = 0; i < 4; ++i) {
                float p = s[i][j];
                #pragma unroll
                for (int dd = 0; dd < 16; ++dd) o[i][dd] += p * va[dd];
            }
        }
    }

    // merge partial O across the 16-lane row group, normalize, stage to LDS
    #pragma unroll
    for (int i = 0; i < 4; ++i) {
        float linv = 1.0f / l[i];
        #pragma unroll
        for (int dd = 0; dd < 16; ++dd) {
            float v = o[i][dd];
            v += __shfl_xor(v, 1, 16);
            v += __shfl_xor(v, 2, 16);
            v += __shfl_xor(v, 4, 16);
            v += __shfl_xor(v, 8, 16);
            if (tx == 0) Ob[ty * 4 + i][dd] = v * linv;
        }
    }
    __syncthreads();

    // coalesced write: out[b, hh*512 + nn/4, 256 + (nn%4)*16 + dd]
    #pragma unroll
    for (int e = t; e < 1024; e += 256) {
        int r = e >> 4, dd = e & 15;
        int nn = rt * 64 + r;
        int n = hh * 512 + (nn >> 2);
        int cc = 256 + ((nn & 3) << 4) + dd;
        out[((size_t)b * Nn + n) * 320 + cc] = Ob[r][dd];
    }
}

// ---------------------------------------------------------------------------
extern "C" void kernel_launch(void* const* d_in, const int* in_sizes, int n_in,
                              void* d_out, int out_size, void* d_ws, size_t ws_size,
                              hipStream_t stream)
{
    const float* s    = (const float*)d_in[0];
    const float* h    = (const float*)d_in[1];
    const float* sh   = (const float*)d_in[2];
    const float* temp  = (const float*)d_in[3];
    const float* temp2 = (const float*)d_in[4];
    const float* Wq_c = (const float*)d_in[5];
    const float* Wq_s = (const float*)d_in[6];
    const float* Wk_c = (const float*)d_in[7];
    const float* Wv_c = (const float*)d_in[8];
    const float* Wk_s = (const float*)d_in[9];
    const float* Wv_s = (const float*)d_in[10];
    float* out = (float*)d_out;
    float* ws = (float*)d_ws;

    float* Pqc = ws + OFF_QC;
    float* Pqs = ws + OFF_QS;
    float* Pkc = ws + OFF_KC;
    float* Pvc = ws + OFF_VC;
    float* Pks = ws + OFF_KS;
    float* Pvs = ws + OFF_VS;
    float* part = ws + OFF_PART;
    float* Sca = ws + OFF_SCA;

    const dim3 blk(256);
    const int M = Bb * Nn;  // 8192

    // projections: x @ W^T
    gemm_xwt<<<dim3(4, 128), blk, 0, stream>>>(s,  Wq_c, Pqc, M, 256, 256);
    gemm_xwt<<<dim3(4, 128), blk, 0, stream>>>(sh, Wq_s, Pqs, M, 256, 256);
    gemm_xwt<<<dim3(4, 128), blk, 0, stream>>>(sh, Wk_c, Pkc, M, 256, 256);
    gemm_xwt<<<dim3(4, 128), blk, 0, stream>>>(sh, Wv_c, Pvc, M, 256, 256);
    gemm_xwt<<<dim3(4, 128), blk, 0, stream>>>(sh, Wk_s, Pks, M, 256, 256);
    gemm_xwt<<<dim3(1, 128), blk, 0, stream>>>(h,  Wv_s, Pvs, M, 64, 64);

    // channel branch
    chan_qk_partial<<<dim3(8, 4, 4), blk, 0, stream>>>(Pqc, Pkc, part);
    chan_softmax<<<dim3(16), dim3(64), 0, stream>>>(part, temp, Sca);
    chan_out<<<dim3(8, 4, 4), blk, 0, stream>>>(Sca, Pvc, out);

    // spatial branch
    spatial_attn<<<dim3(32, 4, 4), blk, 0, stream>>>(Pqs, Pks, Pvs, temp2, out);
}

// Round 2
// 261.258 us; speedup vs baseline: 1.5967x; 1.5967x over previous
//
#include <hip/hip_runtime.h>
#include <math.h>

// ---------------------------------------------------------------------------
// WCSA round 2: spatial branch -> MFMA bf16 (16x16x32). Channel branch and
// projections stay f32; spatial projections store bf16 outputs.
// Head semantics (raw reshape): head hh of batch b = contiguous slice at
// offset b*N*C + hh*N*d of the (B*N, C) projection, viewed (N, d) row-major.
// ---------------------------------------------------------------------------

constexpr int Bb = 4, Nn = 2048, Hh = 4;
constexpr int PROJ_B = Nn * 256;
constexpr int HEAD_C = Nn * 64;

// workspace layout (float-granular offsets; bf16 regions just use half)
constexpr size_t OFF_QC   = 0;
constexpr size_t OFF_QS   = OFF_QC + (size_t)Bb * PROJ_B;
constexpr size_t OFF_KC   = OFF_QS + (size_t)Bb * PROJ_B;
constexpr size_t OFF_VC   = OFF_KC + (size_t)Bb * PROJ_B;
constexpr size_t OFF_KS   = OFF_VC + (size_t)Bb * PROJ_B;
constexpr size_t OFF_VS   = OFF_KS + (size_t)Bb * PROJ_B;
constexpr size_t OFF_PART = OFF_VS + (size_t)Bb * Nn * 64;
constexpr size_t OFF_SCA  = OFF_PART + (size_t)16 * 8 * 4096;

typedef __attribute__((ext_vector_type(8))) short short8_t;   // 8 bf16 = 4 VGPR
typedef __attribute__((ext_vector_type(4))) short short4_t;
typedef __attribute__((ext_vector_type(4))) float f32x4;

__device__ __forceinline__ ushort f2bf(float x) {
    union { float f; unsigned u; } v; v.f = x;
    unsigned r = v.u + 0x7fffu + ((v.u >> 16) & 1u);   // RNE
    return (ushort)(r >> 16);
}

// ---------------------------------------------------------------------------
// C[M,N] = X[M,K] @ W[N,K]^T. 64x64 tile, BK=32, f32 compute.
// BF16 out: store bf16 (for spatial branch consumers).
// ---------------------------------------------------------------------------
template<bool BF16OUT>
__global__ __launch_bounds__(256) void gemm_xwt(const float* __restrict__ X,
                                                const float* __restrict__ W,
                                                void* __restrict__ Cout,
                                                int M, int N, int K)
{
    __shared__ float Xs[32][68];
    __shared__ float Ws[32][68];
    const int t = threadIdx.x;
    const int ty = t >> 4, tx = t & 15;
    const int m0 = blockIdx.y * 64, n0 = blockIdx.x * 64;

    float acc[4][4] = {};
    for (int k0 = 0; k0 < K; k0 += 32) {
        __syncthreads();
        #pragma unroll
        for (int q = t; q < 512; q += 256) {
            int row = q >> 3, c4 = q & 7;
            float4 f = *(const float4*)&X[(size_t)(m0 + row) * K + k0 + c4 * 4];
            Xs[c4 * 4 + 0][row] = f.x; Xs[c4 * 4 + 1][row] = f.y;
            Xs[c4 * 4 + 2][row] = f.z; Xs[c4 * 4 + 3][row] = f.w;
            float4 g = *(const float4*)&W[(size_t)(n0 + row) * K + k0 + c4 * 4];
            Ws[c4 * 4 + 0][row] = g.x; Ws[c4 * 4 + 1][row] = g.y;
            Ws[c4 * 4 + 2][row] = g.z; Ws[c4 * 4 + 3][row] = g.w;
        }
        __syncthreads();
        #pragma unroll 8
        for (int kk = 0; kk < 32; ++kk) {
            float4 x4 = *(const float4*)&Xs[kk][ty * 4];
            float4 w4 = *(const float4*)&Ws[kk][tx * 4];
            float xa[4] = {x4.x, x4.y, x4.z, x4.w};
            float wa[4] = {w4.x, w4.y, w4.z, w4.w};
            #pragma unroll
            for (int ii = 0; ii < 4; ++ii)
                #pragma unroll
                for (int jj = 0; jj < 4; ++jj)
                    acc[ii][jj] += xa[ii] * wa[jj];
        }
    }
    #pragma unroll
    for (int ii = 0; ii < 4; ++ii) {
        size_t idx = (size_t)(m0 + ty * 4 + ii) * N + n0 + tx * 4;
        if constexpr (BF16OUT) {
            ushort4 r4;
            r4.x = f2bf(acc[ii][0]); r4.y = f2bf(acc[ii][1]);
            r4.z = f2bf(acc[ii][2]); r4.w = f2bf(acc[ii][3]);
            *(ushort4*)&((ushort*)Cout)[idx] = r4;
        } else {
            *(float4*)&((float*)Cout)[idx] =
                make_float4(acc[ii][0], acc[ii][1], acc[ii][2], acc[ii][3]);
        }
    }
}

// ---------------------------------------------------------------------------
// Channel stage 1: partial S over 256-row chunk (f32). grid=(8,4,4).
// ---------------------------------------------------------------------------
__global__ __launch_bounds__(256) void chan_qk_partial(const float* __restrict__ Pqc,
                                                       const float* __restrict__ Pkc,
                                                       float* __restrict__ part)
{
    const int ch = blockIdx.x, hh = blockIdx.y, b = blockIdx.z;
    const float* Q = Pqc + (size_t)b * PROJ_B + (size_t)hh * HEAD_C;
    const float* Kk = Pkc + (size_t)b * PROJ_B + (size_t)hh * HEAD_C;
    __shared__ float Qs[64][68], Ks[64][68];
    const int t = threadIdx.x, ty = t >> 4, tx = t & 15;

    float acc[4][4] = {};
    for (int sub = 0; sub < 4; ++sub) {
        const int r0 = ch * 256 + sub * 64;
        __syncthreads();
        #pragma unroll
        for (int q = t; q < 1024; q += 256) {
            int row = q >> 4, c4 = q & 15;
            *(float4*)&Qs[row][c4 * 4] = *(const float4*)&Q[(size_t)(r0 + row) * 64 + c4 * 4];
            *(float4*)&Ks[row][c4 * 4] = *(const float4*)&Kk[(size_t)(r0 + row) * 64 + c4 * 4];
        }
        __syncthreads();
        #pragma unroll 8
        for (int nn = 0; nn < 64; ++nn) {
            float4 q4 = *(const float4*)&Qs[nn][ty * 4];
            float4 k4 = *(const float4*)&Ks[nn][tx * 4];
            float qa[4] = {q4.x, q4.y, q4.z, q4.w};
            float ka[4] = {k4.x, k4.y, k4.z, k4.w};
            #pragma unroll
            for (int ii = 0; ii < 4; ++ii)
                #pragma unroll
                for (int jj = 0; jj < 4; ++jj)
                    acc[ii][jj] += qa[ii] * ka[jj];
        }
    }
    float* P = part + (((size_t)(b * 4 + hh) * 8 + ch) << 12);
    #pragma unroll
    for (int ii = 0; ii < 4; ++ii) {
        float4 r = make_float4(acc[ii][0], acc[ii][1], acc[ii][2], acc[ii][3]);
        *(float4*)&P[(ty * 4 + ii) * 64 + tx * 4] = r;
    }
}

// ---------------------------------------------------------------------------
// Channel stage 2: reduce 8 partials, scale, softmax rows. grid=16 x 64 thr.
// ---------------------------------------------------------------------------
__global__ __launch_bounds__(64) void chan_softmax(const float* __restrict__ part,
                                                   const float* __restrict__ temp,
                                                   float* __restrict__ Sca)
{
    const int bh = blockIdx.x;
    const int h = bh & 3;
    const int i = threadIdx.x;
    __shared__ float Ss[64][65];
    const float sT = 0.125f * temp[h];

    float m = -1e30f;
    for (int j = 0; j < 64; ++j) {
        float v = 0.f;
        #pragma unroll
        for (int c = 0; c < 8; ++c)
            v += part[((size_t)bh * 8 + c) * 4096 + i * 64 + j];
        v *= sT;
        Ss[i][j] = v;
        m = fmaxf(m, v);
    }
    float sum = 0.f;
    for (int j = 0; j < 64; ++j) {
        float p = __expf(Ss[i][j] - m);
        Ss[i][j] = p;
        sum += p;
    }
    const float inv = 1.0f / sum;
    for (int j = 0; j < 64; ++j)
        Sca[((size_t)bh << 12) + i * 64 + j] = Ss[i][j] * inv;
}

// ---------------------------------------------------------------------------
// Channel stage 3: x_ca scatter (f32). grid=(8,4,4).
// ---------------------------------------------------------------------------
__global__ __launch_bounds__(256) void chan_out(const float* __restrict__ Sca,
                                                const float* __restrict__ Pvc,
                                                float* __restrict__ out)
{
    const int nc = blockIdx.x, hh = blockIdx.y, b = blockIdx.z;
    __shared__ float Ss[64][68];
    const int t = threadIdx.x;
    const float* S = Sca + ((size_t)(b * 4 + hh) << 12);
    #pragma unroll
    for (int q = t; q < 1024; q += 256) {
        int dr = q >> 4, c4 = q & 15;
        *(float4*)&Ss[dr][c4 * 4] = *(const float4*)&S[dr * 64 + c4 * 4];
    }
    __syncthreads();

    const float* V = Pvc + (size_t)b * PROJ_B + (size_t)hh * HEAD_C;
    const int nn = nc * 256 + t;
    float v[64];
    const float4* vp = (const float4*)&V[(size_t)nn * 64];
    #pragma unroll
    for (int q = 0; q < 16; ++q) {
        float4 f = vp[q];
        v[q * 4] = f.x; v[q * 4 + 1] = f.y; v[q * 4 + 2] = f.z; v[q * 4 + 3] = f.w;
    }
    float* ob = out + (size_t)b * (Nn * 320);
    #pragma unroll 4
    for (int dr = 0; dr < 64; ++dr) {
        float a = 0.f;
        #pragma unroll
        for (int d4 = 0; d4 < 16; ++d4) {
            float4 s4 = *(const float4*)&Ss[dr][d4 * 4];
            a += s4.x * v[d4 * 4] + s4.y * v[d4 * 4 + 1]
               + s4.z * v[d4 * 4 + 2] + s4.w * v[d4 * 4 + 3];
        }
        int rem = hh * 131072 + dr * 2048 + nn;
        ob[(rem >> 8) * 320 + (rem & 255)] = a;
    }
}

// ---------------------------------------------------------------------------
// Spatial branch via MFMA bf16. Per block: 64 q-rows (4 waves x 16), loop over
// 32 KV blocks of 64. Fragment conventions (C = A*B^T form):
//   a_frag: lane holds A[l&15][8*(l>>4)+e], e=0..7 (one k-chunk of 32)
//   b_frag: lane holds Bmat[8*(l>>4)+e][l&15]  (= rows of B when C=A*B^T)
//   C/D:    lane reg r holds C[(l>>4)*4 + r][l&15]   [verified m89/m91]
// K_lds/P_lds/Vt_lds padded to 72 shorts (=144B = 9*16B): 16B-aligned rows,
// <=2-way bank aliasing on b64 reads (free per m136).
// ---------------------------------------------------------------------------
__global__ __launch_bounds__(256) void spatial_attn_mfma(const ushort* __restrict__ Pqs,
                                                         const ushort* __restrict__ Pks,
                                                         const ushort* __restrict__ Pvs,
                                                         const float* __restrict__ temp2,
                                                         float* __restrict__ out)
{
    const int rt = blockIdx.x, hh = blockIdx.y, b = blockIdx.z;
    const int t = threadIdx.x;
    const int w = t >> 6, l = t & 63;
    const int c = l & 15, g = l >> 4;

    __shared__ ushort K_lds[64][72];
    __shared__ ushort Vt_lds[16][72];
    __shared__ ushort P_lds[4][16][72];

    const ushort* Qh = Pqs + (size_t)b * PROJ_B + (size_t)hh * HEAD_C;
    const ushort* Kh = Pks + (size_t)b * PROJ_B + (size_t)hh * HEAD_C;
    const ushort* Vh = Pvs + (size_t)b * (Nn * 64) + (size_t)hh * (Nn * 16);
    const float sT = 0.125f * temp2[hh];

    // Q fragments for this wave's 16 rows, kept in registers all kernel.
    const ushort* qp = Qh + (size_t)(rt * 64 + w * 16 + c) * 64 + 8 * g;
    const short8_t qf0 = *(const short8_t*)qp;
    const short8_t qf1 = *(const short8_t*)(qp + 32);

    float m_r[4], l_r[4];
    f32x4 o_acc = {0.f, 0.f, 0.f, 0.f};
    #pragma unroll
    for (int r = 0; r < 4; ++r) { m_r[r] = -1e30f; l_r[r] = 0.f; }

    const int krow = t >> 2, kseg = t & 3;      // K staging: 4 threads/row
    const int vrow = t >> 2, vc4 = t & 3;       // V staging

    for (int kc = 0; kc < 32; ++kc) {
        __syncthreads();
        // stage K block (64x64 bf16) coalesced, padded rows
        {
            const ushort* src = Kh + (size_t)(kc * 64 + krow) * 64 + kseg * 16;
            short8_t a = *(const short8_t*)src;
            short8_t bb = *(const short8_t*)(src + 8);
            *(short8_t*)&K_lds[krow][kseg * 16] = a;
            *(short8_t*)&K_lds[krow][kseg * 16 + 8] = bb;
        }
        // stage V^T (16 x 64)
        {
            const ushort* vs = Vh + (size_t)(kc * 64 + vrow) * 16 + vc4 * 4;
            short4_t vv = *(const short4_t*)vs;
            #pragma unroll
            for (int j = 0; j < 4; ++j) Vt_lds[vc4 * 4 + j][vrow] = (ushort)vv[j];
        }
        __syncthreads();

        // S(16x64) = Q * K^T : 4 col-tiles x 2 k-chunks
        f32x4 s[4];
        #pragma unroll
        for (int tc = 0; tc < 4; ++tc) {
            short8_t kb0 = *(const short8_t*)&K_lds[tc * 16 + c][8 * g];
            short8_t kb1 = *(const short8_t*)&K_lds[tc * 16 + c][32 + 8 * g];
            f32x4 st = {0.f, 0.f, 0.f, 0.f};
            st = __builtin_amdgcn_mfma_f32_16x16x32_bf16(qf0, kb0, st, 0, 0, 0);
            st = __builtin_amdgcn_mfma_f32_16x16x32_bf16(qf1, kb1, st, 0, 0, 0);
            s[tc] = st;
        }

        // online softmax: lane owns 4 rows (4g+r), cols 16*tc + c
        #pragma unroll
        for (int r = 0; r < 4; ++r) {
            float a0 = s[0][r] * sT, a1 = s[1][r] * sT;
            float a2 = s[2][r] * sT, a3 = s[3][r] * sT;
            float cm = fmaxf(fmaxf(a0, a1), fmaxf(a2, a3));
            cm = fmaxf(cm, __shfl_xor(cm, 1, 16));
            cm = fmaxf(cm, __shfl_xor(cm, 2, 16));
            cm = fmaxf(cm, __shfl_xor(cm, 4, 16));
            cm = fmaxf(cm, __shfl_xor(cm, 8, 16));
            float mn = fmaxf(m_r[r], cm);
            float corr = __expf(m_r[r] - mn);
            float p0 = __expf(a0 - mn), p1 = __expf(a1 - mn);
            float p2 = __expf(a2 - mn), p3 = __expf(a3 - mn);
            float ps = p0 + p1 + p2 + p3;
            ps += __shfl_xor(ps, 1, 16);
            ps += __shfl_xor(ps, 2, 16);
            ps += __shfl_xor(ps, 4, 16);
            ps += __shfl_xor(ps, 8, 16);
            l_r[r] = l_r[r] * corr + ps;
            m_r[r] = mn;
            o_acc[r] *= corr;
            ushort* pr = &P_lds[w][4 * g + r][c];
            pr[0]  = f2bf(p0);
            pr[16] = f2bf(p1);
            pr[32] = f2bf(p2);
            pr[48] = f2bf(p3);
        }

        // O(16x16) += P(16x64) * V(64x16); per-wave P buffer (no barrier:
        // same-wave LDS RAW handled by compiler lgkmcnt)
        {
            short8_t pa0 = *(const short8_t*)&P_lds[w][c][8 * g];
            short8_t pa1 = *(const short8_t*)&P_lds[w][c][32 + 8 * g];
            short8_t vb0 = *(const short8_t*)&Vt_lds[c][8 * g];
            short8_t vb1 = *(const short8_t*)&Vt_lds[c][32 + 8 * g];
            o_acc = __builtin_amdgcn_mfma_f32_16x16x32_bf16(pa0, vb0, o_acc, 0, 0, 0);
            o_acc = __builtin_amdgcn_mfma_f32_16x16x32_bf16(pa1, vb1, o_acc, 0, 0, 0);
        }
    }

    // epilogue: normalize and scatter per raw-reshape mapping
    #pragma unroll
    for (int r = 0; r < 4; ++r) {
        float val = o_acc[r] / l_r[r];
        int nn = rt * 64 + w * 16 + 4 * g + r;
        int n = hh * 512 + (nn >> 2);
        int cc = 256 + ((nn & 3) << 4) + c;
        out[((size_t)b * Nn + n) * 320 + cc] = val;
    }
}

// ---------------------------------------------------------------------------
extern "C" void kernel_launch(void* const* d_in, const int* in_sizes, int n_in,
                              void* d_out, int out_size, void* d_ws, size_t ws_size,
                              hipStream_t stream)
{
    const float* s     = (const float*)d_in[0];
    const float* h     = (const float*)d_in[1];
    const float* sh    = (const float*)d_in[2];
    const float* temp  = (const float*)d_in[3];
    const float* temp2 = (const float*)d_in[4];
    const float* Wq_c  = (const float*)d_in[5];
    const float* Wq_s  = (const float*)d_in[6];
    const float* Wk_c  = (const float*)d_in[7];
    const float* Wv_c  = (const float*)d_in[8];
    const float* Wk_s  = (const float*)d_in[9];
    const float* Wv_s  = (const float*)d_in[10];
    float* out = (float*)d_out;
    float* ws = (float*)d_ws;

    float* Pqc = ws + OFF_QC;
    ushort* Pqs = (ushort*)(ws + OFF_QS);
    float* Pkc = ws + OFF_KC;
    float* Pvc = ws + OFF_VC;
    ushort* Pks = (ushort*)(ws + OFF_KS);
    ushort* Pvs = (ushort*)(ws + OFF_VS);
    float* part = ws + OFF_PART;
    float* Sca  = ws + OFF_SCA;

    const dim3 blk(256);
    const int M = Bb * Nn;  // 8192

    // projections: x @ W^T  (channel: f32 out; spatial: bf16 out)
    gemm_xwt<false><<<dim3(4, 128), blk, 0, stream>>>(s,  Wq_c, Pqc, M, 256, 256);
    gemm_xwt<true ><<<dim3(4, 128), blk, 0, stream>>>(sh, Wq_s, Pqs, M, 256, 256);
    gemm_xwt<false><<<dim3(4, 128), blk, 0, stream>>>(sh, Wk_c, Pkc, M, 256, 256);
    gemm_xwt<false><<<dim3(4, 128), blk, 0, stream>>>(sh, Wv_c, Pvc, M, 256, 256);
    gemm_xwt<true ><<<dim3(4, 128), blk, 0, stream>>>(sh, Wk_s, Pks, M, 256, 256);
    gemm_xwt<true ><<<dim3(1, 128), blk, 0, stream>>>(h,  Wv_s, Pvs, M, 64, 64);

    // channel branch (f32)
    chan_qk_partial<<<dim3(8, 4, 4), blk, 0, stream>>>(Pqc, Pkc, part);
    chan_softmax<<<dim3(16), dim3(64), 0, stream>>>(part, temp, Sca);
    chan_out<<<dim3(8, 4, 4), blk, 0, stream>>>(Sca, Pvc, out);

    // spatial branch (MFMA bf16)
    spatial_attn_mfma<<<dim3(32, 4, 4), blk, 0, stream>>>(Pqs, Pks, Pvs, temp2, out);
}

// Round 3
// 136.641 us; speedup vs baseline: 3.0528x; 1.9120x over previous
//
#include <hip/hip_runtime.h>
#include <math.h>

// ---------------------------------------------------------------------------
// WCSA round 3: bf16 MFMA projections (fused 4-way sh-GEMM), bf16 channel
// branch (MFMA PV), spatial branch unchanged from round 2 (verified).
// Head semantics (raw reshape): head hh of batch b = contiguous slice at
// element offset b*N*C + hh*N*d of the (B*N, C) projection, viewed (N, d).
// ---------------------------------------------------------------------------

constexpr int Bb = 4, Nn = 2048, Hh = 4;
constexpr int PROJ_EL = Nn * 256;          // elements per batch, 256-col proj
constexpr int HEAD_EL = Nn * 64;           // elements per (b,h) head, d=64

typedef __attribute__((ext_vector_type(8))) short short8_t;   // 8 bf16
typedef __attribute__((ext_vector_type(4))) short short4_t;
typedef __attribute__((ext_vector_type(4))) float f32x4;

__device__ __forceinline__ ushort f2bf(float x) {
    union { float f; unsigned u; } v; v.f = x;
    unsigned r = v.u + 0x7fffu + ((v.u >> 16) & 1u);   // RNE
    return (ushort)(r >> 16);
}
__device__ __forceinline__ float bf2f(ushort x) {
    union { unsigned u; float f; } v; v.u = ((unsigned)x) << 16;
    return v.f;
}

// ---------------- workspace layout (float granularity) ---------------------
constexpr size_t OFF_SB    = 0;                                   // s bf16: 2M el
constexpr size_t OFF_SHB   = OFF_SB   + 1024 * 1024;              // sh bf16
constexpr size_t OFF_HB    = OFF_SHB  + 1024 * 1024;              // h bf16: 512K el
constexpr size_t OFF_WQC   = OFF_HB   + 256 * 1024;               // Wq_c bf16: 64K el
constexpr size_t OFF_WCAT  = OFF_WQC  + 32 * 1024;                // 4 x 64K el
constexpr size_t OFF_PQC   = OFF_WCAT + 128 * 1024;               // bf16 (8192,256)
constexpr size_t OFF_PQS   = OFF_PQC  + 1024 * 1024;
constexpr size_t OFF_PKC   = OFF_PQS  + 1024 * 1024;
constexpr size_t OFF_PVC   = OFF_PKC  + 1024 * 1024;
constexpr size_t OFF_PKS   = OFF_PVC  + 1024 * 1024;
constexpr size_t OFF_PVS   = OFF_PKS  + 1024 * 1024;              // bf16 (8192,64)
constexpr size_t OFF_PART  = OFF_PVS  + 256 * 1024;               // f32 16*8*4096
constexpr size_t OFF_SCA   = OFF_PART + 512 * 1024;               // bf16 16*4096

// ---------------------------------------------------------------------------
// Convert all needed f32 arrays to bf16 in one pass. 8 elements per thread.
// Segment boundaries are compile-time constants (all multiples of 8).
// ---------------------------------------------------------------------------
constexpr unsigned SEG0 = 2097152;              // s
constexpr unsigned SEG1 = SEG0 + 2097152;       // sh
constexpr unsigned SEG2 = SEG1 + 524288;        // h
constexpr unsigned SEG3 = SEG2 + 65536;         // Wq_c
constexpr unsigned SEG4 = SEG3 + 65536;         // Wq_s  -> Wcat+0
constexpr unsigned SEG5 = SEG4 + 65536;         // Wk_c  -> Wcat+65536
constexpr unsigned SEG6 = SEG5 + 65536;         // Wv_c  -> Wcat+131072
constexpr unsigned SEG7 = SEG6 + 65536;         // Wk_s  -> Wcat+196608
constexpr unsigned CVT_THREADS = SEG7 / 8;      // 630784 = 2464 * 256

__global__ __launch_bounds__(256) void convert_all(
    const float* __restrict__ s, const float* __restrict__ sh,
    const float* __restrict__ h, const float* __restrict__ wqc,
    const float* __restrict__ wqs, const float* __restrict__ wkc,
    const float* __restrict__ wvc, const float* __restrict__ wks,
    ushort* __restrict__ sb, ushort* __restrict__ shb, ushort* __restrict__ hb,
    ushort* __restrict__ wqcb, ushort* __restrict__ wcatb)
{
    unsigned e = (blockIdx.x * 256u + threadIdx.x) * 8u;
    const float* src; ushort* dst; unsigned off;
    if      (e < SEG0) { src = s;   dst = sb;             off = e; }
    else if (e < SEG1) { src = sh;  dst = shb;            off = e - SEG0; }
    else if (e < SEG2) { src = h;   dst = hb;             off = e - SEG1; }
    else if (e < SEG3) { src = wqc; dst = wqcb;           off = e - SEG2; }
    else if (e < SEG4) { src = wqs; dst = wcatb;          off = e - SEG3; }
    else if (e < SEG5) { src = wkc; dst = wcatb + 65536;  off = e - SEG4; }
    else if (e < SEG6) { src = wvc; dst = wcatb + 131072; off = e - SEG5; }
    else               { src = wks; dst = wcatb + 196608; off = e - SEG6; }
    float4 f0 = *(const float4*)&src[off];
    float4 f1 = *(const float4*)&src[off + 4];
    short8_t o;
    o[0] = f2bf(f0.x); o[1] = f2bf(f0.y); o[2] = f2bf(f0.z); o[3] = f2bf(f0.w);
    o[4] = f2bf(f1.x); o[5] = f2bf(f1.y); o[6] = f2bf(f1.z); o[7] = f2bf(f1.w);
    *(short8_t*)&dst[off] = o;
}

// ---------------------------------------------------------------------------
// bf16 MFMA GEMM: C = X(M,K) @ W(Ntot,K)^T, bf16 out, routed to one of four
// 256-col destination buffers by global column segment. 128x128 tile, BK=64,
// 4 waves (2x2), acc 4x4 of 16x16 frags.
// Fragment conv (validated by round-2 spatial kernel on HW):
//   a/b frag lane l: Mat[l&15][8*(l>>4)+e]; C/D lane l reg r: C[4*(l>>4)+r][l&15]
// ---------------------------------------------------------------------------
__global__ __launch_bounds__(256) void mfma_gemm(
    const ushort* __restrict__ X, const ushort* __restrict__ W,
    ushort* __restrict__ d0, ushort* __restrict__ d1,
    ushort* __restrict__ d2, ushort* __restrict__ d3, int K)
{
    __shared__ ushort Xs[128][72];
    __shared__ ushort Ws[128][72];
    const int t = threadIdx.x;
    const int w = t >> 6, l = t & 63, c = l & 15, g = l >> 4;
    const int wr = w >> 1, wc = w & 1;
    const int m0 = blockIdx.y * 128, n0 = blockIdx.x * 128;

    f32x4 acc[4][4] = {};

    const int srow = t >> 2, scs = (t & 3) * 16;
    for (int k0 = 0; k0 < K; k0 += 64) {
        __syncthreads();
        #pragma unroll
        for (int p = 0; p < 2; ++p) {
            const ushort* xs = &X[(size_t)(m0 + p * 64 + srow) * K + k0 + scs];
            *(short8_t*)&Xs[p * 64 + srow][scs]     = *(const short8_t*)xs;
            *(short8_t*)&Xs[p * 64 + srow][scs + 8] = *(const short8_t*)(xs + 8);
            const ushort* wsp = &W[(size_t)(n0 + p * 64 + srow) * K + k0 + scs];
            *(short8_t*)&Ws[p * 64 + srow][scs]     = *(const short8_t*)wsp;
            *(short8_t*)&Ws[p * 64 + srow][scs + 8] = *(const short8_t*)(wsp + 8);
        }
        __syncthreads();
        #pragma unroll
        for (int ks = 0; ks < 2; ++ks) {
            short8_t af[4], bf[4];
            #pragma unroll
            for (int rt = 0; rt < 4; ++rt)
                af[rt] = *(const short8_t*)&Xs[wr * 64 + rt * 16 + c][ks * 32 + 8 * g];
            #pragma unroll
            for (int ct = 0; ct < 4; ++ct)
                bf[ct] = *(const short8_t*)&Ws[wc * 64 + ct * 16 + c][ks * 32 + 8 * g];
            #pragma unroll
            for (int rt = 0; rt < 4; ++rt)
                #pragma unroll
                for (int ct = 0; ct < 4; ++ct)
                    acc[rt][ct] = __builtin_amdgcn_mfma_f32_16x16x32_bf16(
                        af[rt], bf[ct], acc[rt][ct], 0, 0, 0);
        }
    }

    const int seg = n0 >> 8;
    ushort* dst = seg == 0 ? d0 : seg == 1 ? d1 : seg == 2 ? d2 : d3;
    const int colbase = (n0 & 255) + wc * 64;
    #pragma unroll
    for (int rt = 0; rt < 4; ++rt)
        #pragma unroll
        for (int ct = 0; ct < 4; ++ct)
            #pragma unroll
            for (int r = 0; r < 4; ++r) {
                int mrow = m0 + wr * 64 + rt * 16 + 4 * g + r;
                int col = colbase + ct * 16 + c;
                dst[(size_t)mrow * 256 + col] = f2bf(acc[rt][ct][r]);
            }
}

// ---------------------------------------------------------------------------
// f32 GEMM kept for the tiny h @ Wv_s^T (M=8192, N=64, K=64), bf16 out.
// ---------------------------------------------------------------------------
__global__ __launch_bounds__(256) void gemm_xwt_f32bf(const float* __restrict__ X,
                                                      const float* __restrict__ W,
                                                      ushort* __restrict__ Cout,
                                                      int M, int N, int K)
{
    __shared__ float Xs[32][68];
    __shared__ float Wsh[32][68];
    const int t = threadIdx.x;
    const int ty = t >> 4, tx = t & 15;
    const int m0 = blockIdx.y * 64, n0 = blockIdx.x * 64;

    float acc[4][4] = {};
    for (int k0 = 0; k0 < K; k0 += 32) {
        __syncthreads();
        #pragma unroll
        for (int q = t; q < 512; q += 256) {
            int row = q >> 3, c4 = q & 7;
            float4 f = *(const float4*)&X[(size_t)(m0 + row) * K + k0 + c4 * 4];
            Xs[c4 * 4 + 0][row] = f.x; Xs[c4 * 4 + 1][row] = f.y;
            Xs[c4 * 4 + 2][row] = f.z; Xs[c4 * 4 + 3][row] = f.w;
            float4 gg = *(const float4*)&W[(size_t)(n0 + row) * K + k0 + c4 * 4];
            Wsh[c4 * 4 + 0][row] = gg.x; Wsh[c4 * 4 + 1][row] = gg.y;
            Wsh[c4 * 4 + 2][row] = gg.z; Wsh[c4 * 4 + 3][row] = gg.w;
        }
        __syncthreads();
        #pragma unroll 8
        for (int kk = 0; kk < 32; ++kk) {
            float4 x4 = *(const float4*)&Xs[kk][ty * 4];
            float4 w4 = *(const float4*)&Wsh[kk][tx * 4];
            float xa[4] = {x4.x, x4.y, x4.z, x4.w};
            float wa[4] = {w4.x, w4.y, w4.z, w4.w};
            #pragma unroll
            for (int ii = 0; ii < 4; ++ii)
                #pragma unroll
                for (int jj = 0; jj < 4; ++jj)
                    acc[ii][jj] += xa[ii] * wa[jj];
        }
    }
    #pragma unroll
    for (int ii = 0; ii < 4; ++ii) {
        size_t idx = (size_t)(m0 + ty * 4 + ii) * N + n0 + tx * 4;
        ushort4 r4;
        r4.x = f2bf(acc[ii][0]); r4.y = f2bf(acc[ii][1]);
        r4.z = f2bf(acc[ii][2]); r4.w = f2bf(acc[ii][3]);
        *(ushort4*)&Cout[idx] = r4;
    }
}

// ---------------------------------------------------------------------------
// Channel stage 1 (f32 compute, bf16 input): partial S over 256-row chunk.
// ---------------------------------------------------------------------------
__global__ __launch_bounds__(256) void chan_qk_partial(const ushort* __restrict__ Pqc,
                                                       const ushort* __restrict__ Pkc,
                                                       float* __restrict__ part)
{
    const int ch = blockIdx.x, hh = blockIdx.y, b = blockIdx.z;
    const ushort* Q = Pqc + (size_t)b * PROJ_EL + (size_t)hh * HEAD_EL;
    const ushort* Kk = Pkc + (size_t)b * PROJ_EL + (size_t)hh * HEAD_EL;
    __shared__ float Qs[64][68], Ks[64][68];
    const int t = threadIdx.x, ty = t >> 4, tx = t & 15;

    float acc[4][4] = {};
    for (int sub = 0; sub < 4; ++sub) {
        const int r0 = ch * 256 + sub * 64;
        __syncthreads();
        #pragma unroll
        for (int q = t; q < 512; q += 256) {
            int row = q >> 3, c8 = (q & 7) * 8;
            short8_t qv = *(const short8_t*)&Q[(size_t)(r0 + row) * 64 + c8];
            short8_t kv = *(const short8_t*)&Kk[(size_t)(r0 + row) * 64 + c8];
            #pragma unroll
            for (int j = 0; j < 8; ++j) {
                Qs[row][c8 + j] = bf2f((ushort)qv[j]);
                Ks[row][c8 + j] = bf2f((ushort)kv[j]);
            }
        }
        __syncthreads();
        #pragma unroll 8
        for (int nn = 0; nn < 64; ++nn) {
            float4 q4 = *(const float4*)&Qs[nn][ty * 4];
            float4 k4 = *(const float4*)&Ks[nn][tx * 4];
            float qa[4] = {q4.x, q4.y, q4.z, q4.w};
            float ka[4] = {k4.x, k4.y, k4.z, k4.w};
            #pragma unroll
            for (int ii = 0; ii < 4; ++ii)
                #pragma unroll
                for (int jj = 0; jj < 4; ++jj)
                    acc[ii][jj] += qa[ii] * ka[jj];
        }
    }
    float* P = part + (((size_t)(b * 4 + hh) * 8 + ch) << 12);
    #pragma unroll
    for (int ii = 0; ii < 4; ++ii)
        *(float4*)&P[(ty * 4 + ii) * 64 + tx * 4] =
            make_float4(acc[ii][0], acc[ii][1], acc[ii][2], acc[ii][3]);
}

// ---------------------------------------------------------------------------
// Channel stage 2: reduce 8 partials, scale, softmax rows -> bf16 Sca.
// ---------------------------------------------------------------------------
__global__ __launch_bounds__(64) void chan_softmax(const float* __restrict__ part,
                                                   const float* __restrict__ temp,
                                                   ushort* __restrict__ Sca)
{
    const int bh = blockIdx.x;
    const int hsel = bh & 3;
    const int i = threadIdx.x;
    __shared__ float Ss[64][65];
    const float sT = 0.125f * temp[hsel];

    float m = -1e30f;
    for (int j = 0; j < 64; ++j) {
        float v = 0.f;
        #pragma unroll
        for (int cc = 0; cc < 8; ++cc)
            v += part[((size_t)bh * 8 + cc) * 4096 + i * 64 + j];
        v *= sT;
        Ss[i][j] = v;
        m = fmaxf(m, v);
    }
    float sum = 0.f;
    for (int j = 0; j < 64; ++j) {
        float p = __expf(Ss[i][j] - m);
        Ss[i][j] = p;
        sum += p;
    }
    const float inv = 1.0f / sum;
    for (int j = 0; j < 64; ++j)
        Sca[((size_t)bh << 12) + i * 64 + j] = f2bf(Ss[i][j] * inv);
}

// ---------------------------------------------------------------------------
// Channel stage 3 via MFMA, zero LDS: C(64 x 2048) = S(64x64) @ V(2048x64)^T
// per (b,h). Block = 256-col chunk; wave w owns 64 cols. A-frags from Sca
// (contiguous, L2-hot), B-frags from V rows (contiguous 16B/lane, wave reads
// one 2KB block). Scatter per raw-reshape mapping.
// ---------------------------------------------------------------------------
__global__ __launch_bounds__(256) void chan_pv_mfma(const ushort* __restrict__ Sca,
                                                    const ushort* __restrict__ Pvc,
                                                    float* __restrict__ out)
{
    const int nc = blockIdx.x, hh = blockIdx.y, b = blockIdx.z;
    const int t = threadIdx.x;
    const int w = t >> 6, l = t & 63, c = l & 15, g = l >> 4;

    const ushort* S = Sca + ((size_t)(b * 4 + hh) << 12);          // (64,64)
    const ushort* V = Pvc + (size_t)b * PROJ_EL + (size_t)hh * HEAD_EL;  // (2048,64)
    const int n0w = nc * 256 + w * 64;

    f32x4 acc[4][4] = {};   // [row-tile][col-tile]
    #pragma unroll
    for (int ks = 0; ks < 2; ++ks) {
        short8_t af[4], bf[4];
        #pragma unroll
        for (int rt = 0; rt < 4; ++rt)
            af[rt] = *(const short8_t*)&S[(size_t)(rt * 16 + c) * 64 + ks * 32 + 8 * g];
        #pragma unroll
        for (int ct = 0; ct < 4; ++ct)
            bf[ct] = *(const short8_t*)&V[(size_t)(n0w + ct * 16 + c) * 64 + ks * 32 + 8 * g];
        #pragma unroll
        for (int rt = 0; rt < 4; ++rt)
            #pragma unroll
            for (int ct = 0; ct < 4; ++ct)
                acc[rt][ct] = __builtin_amdgcn_mfma_f32_16x16x32_bf16(
                    af[rt], bf[ct], acc[rt][ct], 0, 0, 0);
    }

    float* ob = out + (size_t)b * (Nn * 320);
    #pragma unroll
    for (int rt = 0; rt < 4; ++rt)
        #pragma unroll
        for (int ct = 0; ct < 4; ++ct)
            #pragma unroll
            for (int r = 0; r < 4; ++r) {
                int i = rt * 16 + 4 * g + r;
                int nn = n0w + ct * 16 + c;
                int rem = hh * 131072 + i * 2048 + nn;
                ob[(rem >> 8) * 320 + (rem & 255)] = acc[rt][ct][r];
            }
}

// ---------------------------------------------------------------------------
// Spatial branch via MFMA bf16 (unchanged from round 2, verified).
// ---------------------------------------------------------------------------
__global__ __launch_bounds__(256) void spatial_attn_mfma(const ushort* __restrict__ Pqs,
                                                         const ushort* __restrict__ Pks,
                                                         const ushort* __restrict__ Pvs,
                                                         const float* __restrict__ temp2,
                                                         float* __restrict__ out)
{
    const int rt = blockIdx.x, hh = blockIdx.y, b = blockIdx.z;
    const int t = threadIdx.x;
    const int w = t >> 6, l = t & 63;
    const int c = l & 15, g = l >> 4;

    __shared__ ushort K_lds[64][72];
    __shared__ ushort Vt_lds[16][72];
    __shared__ ushort P_lds[4][16][72];

    const ushort* Qh = Pqs + (size_t)b * PROJ_EL + (size_t)hh * HEAD_EL;
    const ushort* Kh = Pks + (size_t)b * PROJ_EL + (size_t)hh * HEAD_EL;
    const ushort* Vh = Pvs + (size_t)b * (Nn * 64) + (size_t)hh * (Nn * 16);
    const float sT = 0.125f * temp2[hh];

    const ushort* qp = Qh + (size_t)(rt * 64 + w * 16 + c) * 64 + 8 * g;
    const short8_t qf0 = *(const short8_t*)qp;
    const short8_t qf1 = *(const short8_t*)(qp + 32);

    float m_r[4], l_r[4];
    f32x4 o_acc = {0.f, 0.f, 0.f, 0.f};
    #pragma unroll
    for (int r = 0; r < 4; ++r) { m_r[r] = -1e30f; l_r[r] = 0.f; }

    const int krow = t >> 2, kseg = t & 3;
    const int vrow = t >> 2, vc4 = t & 3;

    for (int kc = 0; kc < 32; ++kc) {
        __syncthreads();
        {
            const ushort* src = Kh + (size_t)(kc * 64 + krow) * 64 + kseg * 16;
            short8_t a = *(const short8_t*)src;
            short8_t bb = *(const short8_t*)(src + 8);
            *(short8_t*)&K_lds[krow][kseg * 16] = a;
            *(short8_t*)&K_lds[krow][kseg * 16 + 8] = bb;
        }
        {
            const ushort* vs = Vh + (size_t)(kc * 64 + vrow) * 16 + vc4 * 4;
            short4_t vv = *(const short4_t*)vs;
            #pragma unroll
            for (int j = 0; j < 4; ++j) Vt_lds[vc4 * 4 + j][vrow] = (ushort)vv[j];
        }
        __syncthreads();

        f32x4 s[4];
        #pragma unroll
        for (int tc = 0; tc < 4; ++tc) {
            short8_t kb0 = *(const short8_t*)&K_lds[tc * 16 + c][8 * g];
            short8_t kb1 = *(const short8_t*)&K_lds[tc * 16 + c][32 + 8 * g];
            f32x4 st = {0.f, 0.f, 0.f, 0.f};
            st = __builtin_amdgcn_mfma_f32_16x16x32_bf16(qf0, kb0, st, 0, 0, 0);
            st = __builtin_amdgcn_mfma_f32_16x16x32_bf16(qf1, kb1, st, 0, 0, 0);
            s[tc] = st;
        }

        #pragma unroll
        for (int r = 0; r < 4; ++r) {
            float a0 = s[0][r] * sT, a1 = s[1][r] * sT;
            float a2 = s[2][r] * sT, a3 = s[3][r] * sT;
            float cm = fmaxf(fmaxf(a0, a1), fmaxf(a2, a3));
            cm = fmaxf(cm, __shfl_xor(cm, 1, 16));
            cm = fmaxf(cm, __shfl_xor(cm, 2, 16));
            cm = fmaxf(cm, __shfl_xor(cm, 4, 16));
            cm = fmaxf(cm, __shfl_xor(cm, 8, 16));
            float mn = fmaxf(m_r[r], cm);
            float corr = __expf(m_r[r] - mn);
            float p0 = __expf(a0 - mn), p1 = __expf(a1 - mn);
            float p2 = __expf(a2 - mn), p3 = __expf(a3 - mn);
            float ps = p0 + p1 + p2 + p3;
            ps += __shfl_xor(ps, 1, 16);
            ps += __shfl_xor(ps, 2, 16);
            ps += __shfl_xor(ps, 4, 16);
            ps += __shfl_xor(ps, 8, 16);
            l_r[r] = l_r[r] * corr + ps;
            m_r[r] = mn;
            o_acc[r] *= corr;
            ushort* pr = &P_lds[w][4 * g + r][c];
            pr[0]  = f2bf(p0);
            pr[16] = f2bf(p1);
            pr[32] = f2bf(p2);
            pr[48] = f2bf(p3);
        }

        {
            short8_t pa0 = *(const short8_t*)&P_lds[w][c][8 * g];
            short8_t pa1 = *(const short8_t*)&P_lds[w][c][32 + 8 * g];
            short8_t vb0 = *(const short8_t*)&Vt_lds[c][8 * g];
            short8_t vb1 = *(const short8_t*)&Vt_lds[c][32 + 8 * g];
            o_acc = __builtin_amdgcn_mfma_f32_16x16x32_bf16(pa0, vb0, o_acc, 0, 0, 0);
            o_acc = __builtin_amdgcn_mfma_f32_16x16x32_bf16(pa1, vb1, o_acc, 0, 0, 0);
        }
    }

    #pragma unroll
    for (int r = 0; r < 4; ++r) {
        float val = o_acc[r] / l_r[r];
        int nn = rt * 64 + w * 16 + 4 * g + r;
        int n = hh * 512 + (nn >> 2);
        int cc = 256 + ((nn & 3) << 4) + c;
        out[((size_t)b * Nn + n) * 320 + cc] = val;
    }
}

// ---------------------------------------------------------------------------
extern "C" void kernel_launch(void* const* d_in, const int* in_sizes, int n_in,
                              void* d_out, int out_size, void* d_ws, size_t ws_size,
                              hipStream_t stream)
{
    const float* s     = (const float*)d_in[0];
    const float* h     = (const float*)d_in[1];
    const float* sh    = (const float*)d_in[2];
    const float* temp  = (const float*)d_in[3];
    const float* temp2 = (const float*)d_in[4];
    const float* Wq_c  = (const float*)d_in[5];
    const float* Wq_s  = (const float*)d_in[6];
    const float* Wk_c  = (const float*)d_in[7];
    const float* Wv_c  = (const float*)d_in[8];
    const float* Wk_s  = (const float*)d_in[9];
    const float* Wv_s  = (const float*)d_in[10];
    float* out = (float*)d_out;
    float* ws = (float*)d_ws;

    ushort* sb    = (ushort*)(ws + OFF_SB);
    ushort* shb   = (ushort*)(ws + OFF_SHB);
    ushort* hb    = (ushort*)(ws + OFF_HB);   // bf16 h (unused by f32 gemm, kept for future)
    ushort* wqcb  = (ushort*)(ws + OFF_WQC);
    ushort* wcatb = (ushort*)(ws + OFF_WCAT);
    ushort* Pqc   = (ushort*)(ws + OFF_PQC);
    ushort* Pqs   = (ushort*)(ws + OFF_PQS);
    ushort* Pkc   = (ushort*)(ws + OFF_PKC);
    ushort* Pvc   = (ushort*)(ws + OFF_PVC);
    ushort* Pks   = (ushort*)(ws + OFF_PKS);
    ushort* Pvs   = (ushort*)(ws + OFF_PVS);
    float*  part  = ws + OFF_PART;
    ushort* Sca   = (ushort*)(ws + OFF_SCA);

    const dim3 blk(256);

    // 1) f32 -> bf16 conversions (activations + weights)
    convert_all<<<dim3(CVT_THREADS / 256), blk, 0, stream>>>(
        s, sh, h, Wq_c, Wq_s, Wk_c, Wv_c, Wk_s, sb, shb, hb, wqcb, wcatb);

    // 2) projections
    //    sh @ [Wq_s; Wk_c; Wv_c; Wk_s]^T -> Pqs, Pkc, Pvc, Pks (segment-routed)
    mfma_gemm<<<dim3(8, 64), blk, 0, stream>>>(shb, wcatb, Pqs, Pkc, Pvc, Pks, 256);
    //    s @ Wq_c^T -> Pqc
    mfma_gemm<<<dim3(2, 64), blk, 0, stream>>>(sb, wqcb, Pqc, Pqc, Pqc, Pqc, 256);
    //    h @ Wv_s^T -> Pvs (tiny, f32 path)
    gemm_xwt_f32bf<<<dim3(1, 128), blk, 0, stream>>>(h, Wv_s, Pvs, Bb * Nn, 64, 64);

    // 3) channel branch
    chan_qk_partial<<<dim3(8, 4, 4), blk, 0, stream>>>(Pqc, Pkc, part);
    chan_softmax<<<dim3(16), dim3(64), 0, stream>>>(part, temp, Sca);
    chan_pv_mfma<<<dim3(8, 4, 4), blk, 0, stream>>>(Sca, Pvc, out);

    // 4) spatial branch
    spatial_attn_mfma<<<dim3(32, 4, 4), blk, 0, stream>>>(Pqs, Pks, Pvs, temp2, out);
}

// Round 6
// 133.280 us; speedup vs baseline: 3.1298x; 1.0252x over previous
//
#include <hip/hip_runtime.h>
#include <math.h>

// ---------------------------------------------------------------------------
// WCSA round 6 (= round 5 + V^T raw-reshape fix).
// Spatial branch: swapped QK^T (lane-local softmax rows), no max-subtraction
// (|scaled logit| < ~0.1 by construction), no K/V LDS staging (L2-resident
// direct global fragment loads), V pre-transposed per-head honoring the raw
// reshape: V_head[k][d] = projflat[b*131072 + hh*32768 + k*16 + d].
// Projections/channel branch unchanged from round 3 (verified).
// ---------------------------------------------------------------------------

constexpr int Bb = 4, Nn = 2048, Hh = 4;
constexpr int PROJ_EL = Nn * 256;          // elements per batch, 256-col proj
constexpr int HEAD_EL = Nn * 64;           // elements per (b,h) head, d=64

typedef __attribute__((ext_vector_type(8))) short short8_t;   // 8 bf16
typedef __attribute__((ext_vector_type(4))) float f32x4;

__device__ __forceinline__ ushort f2bf(float x) {
    union { float f; unsigned u; } v; v.f = x;
    unsigned r = v.u + 0x7fffu + ((v.u >> 16) & 1u);   // RNE
    return (ushort)(r >> 16);
}
__device__ __forceinline__ float bf2f(ushort x) {
    union { unsigned u; float f; } v; v.u = ((unsigned)x) << 16;
    return v.f;
}

// ---------------- workspace layout (float granularity) ---------------------
constexpr size_t OFF_SB    = 0;                                   // s bf16
constexpr size_t OFF_SHB   = OFF_SB   + 1024 * 1024;              // sh bf16
constexpr size_t OFF_HB    = OFF_SHB  + 1024 * 1024;              // h bf16
constexpr size_t OFF_WQC   = OFF_HB   + 256 * 1024;               // Wq_c bf16
constexpr size_t OFF_WCAT  = OFF_WQC  + 32 * 1024;                // 4x64K el
constexpr size_t OFF_PQC   = OFF_WCAT + 128 * 1024;               // bf16 (8192,256)
constexpr size_t OFF_PQS   = OFF_PQC  + 1024 * 1024;
constexpr size_t OFF_PKC   = OFF_PQS  + 1024 * 1024;
constexpr size_t OFF_PVC   = OFF_PKC  + 1024 * 1024;
constexpr size_t OFF_PKS   = OFF_PVC  + 1024 * 1024;
constexpr size_t OFF_PVST  = OFF_PKS  + 1024 * 1024;              // bf16 (B,H,16,2048)
constexpr size_t OFF_PART  = OFF_PVST + 256 * 1024;               // f32 16*8*4096
constexpr size_t OFF_SCA   = OFF_PART + 512 * 1024;               // bf16 16*4096
constexpr size_t OFF_WVS   = OFF_SCA  + 32 * 1024;                // Wv_s bf16 (64,64)

// ---------------------------------------------------------------------------
// Convert all needed f32 arrays to bf16 in one pass. 8 elements per thread.
// ---------------------------------------------------------------------------
constexpr unsigned SEG0 = 2097152;              // s
constexpr unsigned SEG1 = SEG0 + 2097152;       // sh
constexpr unsigned SEG2 = SEG1 + 524288;        // h
constexpr unsigned SEG3 = SEG2 + 65536;         // Wq_c
constexpr unsigned SEG4 = SEG3 + 65536;         // Wq_s  -> Wcat+0
constexpr unsigned SEG5 = SEG4 + 65536;         // Wk_c  -> Wcat+65536
constexpr unsigned SEG6 = SEG5 + 65536;         // Wv_c  -> Wcat+131072
constexpr unsigned SEG7 = SEG6 + 65536;         // Wk_s  -> Wcat+196608
constexpr unsigned SEG8 = SEG7 + 4096;          // Wv_s

__global__ __launch_bounds__(256) void convert_all(
    const float* __restrict__ s, const float* __restrict__ sh,
    const float* __restrict__ h, const float* __restrict__ wqc,
    const float* __restrict__ wqs, const float* __restrict__ wkc,
    const float* __restrict__ wvc, const float* __restrict__ wks,
    const float* __restrict__ wvs,
    ushort* __restrict__ sb, ushort* __restrict__ shb, ushort* __restrict__ hb,
    ushort* __restrict__ wqcb, ushort* __restrict__ wcatb, ushort* __restrict__ wvsb)
{
    unsigned e = (blockIdx.x * 256u + threadIdx.x) * 8u;
    if (e >= SEG8) return;
    const float* src; ushort* dst; unsigned off;
    if      (e < SEG0) { src = s;   dst = sb;             off = e; }
    else if (e < SEG1) { src = sh;  dst = shb;            off = e - SEG0; }
    else if (e < SEG2) { src = h;   dst = hb;             off = e - SEG1; }
    else if (e < SEG3) { src = wqc; dst = wqcb;           off = e - SEG2; }
    else if (e < SEG4) { src = wqs; dst = wcatb;          off = e - SEG3; }
    else if (e < SEG5) { src = wkc; dst = wcatb + 65536;  off = e - SEG4; }
    else if (e < SEG6) { src = wvc; dst = wcatb + 131072; off = e - SEG5; }
    else if (e < SEG7) { src = wks; dst = wcatb + 196608; off = e - SEG6; }
    else               { src = wvs; dst = wvsb;           off = e - SEG7; }
    float4 f0 = *(const float4*)&src[off];
    float4 f1 = *(const float4*)&src[off + 4];
    short8_t o;
    o[0] = f2bf(f0.x); o[1] = f2bf(f0.y); o[2] = f2bf(f0.z); o[3] = f2bf(f0.w);
    o[4] = f2bf(f1.x); o[5] = f2bf(f1.y); o[6] = f2bf(f1.z); o[7] = f2bf(f1.w);
    *(short8_t*)&dst[off] = o;
}

// ---------------------------------------------------------------------------
// bf16 MFMA GEMM: C = X(M,K) @ W(Ntot,K)^T, bf16 out, routed to one of four
// 256-col destination buffers by global column segment. 128x128 tile, BK=64.
// (unchanged from round 3, verified)
// ---------------------------------------------------------------------------
__global__ __launch_bounds__(256) void mfma_gemm(
    const ushort* __restrict__ X, const ushort* __restrict__ W,
    ushort* __restrict__ d0, ushort* __restrict__ d1,
    ushort* __restrict__ d2, ushort* __restrict__ d3, int K)
{
    __shared__ ushort Xs[128][72];
    __shared__ ushort Ws[128][72];
    const int t = threadIdx.x;
    const int w = t >> 6, l = t & 63, c = l & 15, g = l >> 4;
    const int wr = w >> 1, wc = w & 1;
    const int m0 = blockIdx.y * 128, n0 = blockIdx.x * 128;

    f32x4 acc[4][4] = {};

    const int srow = t >> 2, scs = (t & 3) * 16;
    for (int k0 = 0; k0 < K; k0 += 64) {
        __syncthreads();
        #pragma unroll
        for (int p = 0; p < 2; ++p) {
            const ushort* xs = &X[(size_t)(m0 + p * 64 + srow) * K + k0 + scs];
            *(short8_t*)&Xs[p * 64 + srow][scs]     = *(const short8_t*)xs;
            *(short8_t*)&Xs[p * 64 + srow][scs + 8] = *(const short8_t*)(xs + 8);
            const ushort* wsp = &W[(size_t)(n0 + p * 64 + srow) * K + k0 + scs];
            *(short8_t*)&Ws[p * 64 + srow][scs]     = *(const short8_t*)wsp;
            *(short8_t*)&Ws[p * 64 + srow][scs + 8] = *(const short8_t*)(wsp + 8);
        }
        __syncthreads();
        #pragma unroll
        for (int ks = 0; ks < 2; ++ks) {
            short8_t af[4], bf[4];
            #pragma unroll
            for (int rt = 0; rt < 4; ++rt)
                af[rt] = *(const short8_t*)&Xs[wr * 64 + rt * 16 + c][ks * 32 + 8 * g];
            #pragma unroll
            for (int ct = 0; ct < 4; ++ct)
                bf[ct] = *(const short8_t*)&Ws[wc * 64 + ct * 16 + c][ks * 32 + 8 * g];
            #pragma unroll
            for (int rt = 0; rt < 4; ++rt)
                #pragma unroll
                for (int ct = 0; ct < 4; ++ct)
                    acc[rt][ct] = __builtin_amdgcn_mfma_f32_16x16x32_bf16(
                        af[rt], bf[ct], acc[rt][ct], 0, 0, 0);
        }
    }

    const int seg = n0 >> 8;
    ushort* dst = seg == 0 ? d0 : seg == 1 ? d1 : seg == 2 ? d2 : d3;
    const int colbase = (n0 & 255) + wc * 64;
    #pragma unroll
    for (int rt = 0; rt < 4; ++rt)
        #pragma unroll
        for (int ct = 0; ct < 4; ++ct)
            #pragma unroll
            for (int r = 0; r < 4; ++r) {
                int mrow = m0 + wr * 64 + rt * 16 + 4 * g + r;
                int col = colbase + ct * 16 + c;
                dst[(size_t)mrow * 256 + col] = f2bf(acc[rt][ct][r]);
            }
}

// ---------------------------------------------------------------------------
// v_s^T producer with raw-reshape-aware scatter.
// Computes D(64,8192) = Wv_s(64,64) @ h(8192,64)^T = proj^T, then stores each
// element (cc, m) into PvsT[b][hh][d][k] (shape B,H,16,2048) where
//   b = m>>11, n = m&2047, L = n*64+cc, hh = L>>15, k = (L&32767)>>4, d = L&15.
// This is exactly V_head^T[d][k] = projflat[b*131072 + hh*32768 + k*16 + d].
// ---------------------------------------------------------------------------
__global__ __launch_bounds__(256) void mfma_gemm_vs(
    const ushort* __restrict__ Wvs, const ushort* __restrict__ Hb,
    ushort* __restrict__ Cvt)
{
    const int t = threadIdx.x;
    const int w = t >> 6, l = t & 63, c = l & 15, g = l >> 4;
    const int n0 = blockIdx.x * 256 + w * 64;

    f32x4 acc[4][4] = {};
    #pragma unroll
    for (int ks = 0; ks < 2; ++ks) {
        short8_t af[4], bfr[4];
        #pragma unroll
        for (int rt = 0; rt < 4; ++rt)
            af[rt] = *(const short8_t*)&Wvs[(size_t)(rt * 16 + c) * 64 + ks * 32 + 8 * g];
        #pragma unroll
        for (int ct = 0; ct < 4; ++ct)
            bfr[ct] = *(const short8_t*)&Hb[(size_t)(n0 + ct * 16 + c) * 64 + ks * 32 + 8 * g];
        #pragma unroll
        for (int rt = 0; rt < 4; ++rt)
            #pragma unroll
            for (int ct = 0; ct < 4; ++ct)
                acc[rt][ct] = __builtin_amdgcn_mfma_f32_16x16x32_bf16(
                    af[rt], bfr[ct], acc[rt][ct], 0, 0, 0);
    }
    #pragma unroll
    for (int rt = 0; rt < 4; ++rt)
        #pragma unroll
        for (int ct = 0; ct < 4; ++ct)
            #pragma unroll
            for (int r = 0; r < 4; ++r) {
                int cc = rt * 16 + 4 * g + r;       // output channel 0..63
                int m  = n0 + ct * 16 + c;          // global row 0..8191
                int b  = m >> 11, n = m & 2047;
                int L  = n * 64 + cc;               // within-batch flat index
                int hh = L >> 15;
                int k  = (L & 32767) >> 4;
                int d  = L & 15;
                Cvt[(size_t)((b * 4 + hh) * 16 + d) * 2048 + k] = f2bf(acc[rt][ct][r]);
            }
}

// ---------------------------------------------------------------------------
// Channel stage 1 (f32 compute, bf16 input) — unchanged from round 3.
// ---------------------------------------------------------------------------
__global__ __launch_bounds__(256) void chan_qk_partial(const ushort* __restrict__ Pqc,
                                                       const ushort* __restrict__ Pkc,
                                                       float* __restrict__ part)
{
    const int ch = blockIdx.x, hh = blockIdx.y, b = blockIdx.z;
    const ushort* Q = Pqc + (size_t)b * PROJ_EL + (size_t)hh * HEAD_EL;
    const ushort* Kk = Pkc + (size_t)b * PROJ_EL + (size_t)hh * HEAD_EL;
    __shared__ float Qs[64][68], Ks[64][68];
    const int t = threadIdx.x, ty = t >> 4, tx = t & 15;

    float acc[4][4] = {};
    for (int sub = 0; sub < 4; ++sub) {
        const int r0 = ch * 256 + sub * 64;
        __syncthreads();
        #pragma unroll
        for (int q = t; q < 512; q += 256) {
            int row = q >> 3, c8 = (q & 7) * 8;
            short8_t qv = *(const short8_t*)&Q[(size_t)(r0 + row) * 64 + c8];
            short8_t kv = *(const short8_t*)&Kk[(size_t)(r0 + row) * 64 + c8];
            #pragma unroll
            for (int j = 0; j < 8; ++j) {
                Qs[row][c8 + j] = bf2f((ushort)qv[j]);
                Ks[row][c8 + j] = bf2f((ushort)kv[j]);
            }
        }
        __syncthreads();
        #pragma unroll 8
        for (int nn = 0; nn < 64; ++nn) {
            float4 q4 = *(const float4*)&Qs[nn][ty * 4];
            float4 k4 = *(const float4*)&Ks[nn][tx * 4];
            float qa[4] = {q4.x, q4.y, q4.z, q4.w};
            float ka[4] = {k4.x, k4.y, k4.z, k4.w};
            #pragma unroll
            for (int ii = 0; ii < 4; ++ii)
                #pragma unroll
                for (int jj = 0; jj < 4; ++jj)
                    acc[ii][jj] += qa[ii] * ka[jj];
        }
    }
    float* P = part + (((size_t)(b * 4 + hh) * 8 + ch) << 12);
    #pragma unroll
    for (int ii = 0; ii < 4; ++ii)
        *(float4*)&P[(ty * 4 + ii) * 64 + tx * 4] =
            make_float4(acc[ii][0], acc[ii][1], acc[ii][2], acc[ii][3]);
}

// ---------------------------------------------------------------------------
// Channel stage 2 — unchanged from round 3.
// ---------------------------------------------------------------------------
__global__ __launch_bounds__(64) void chan_softmax(const float* __restrict__ part,
                                                   const float* __restrict__ temp,
                                                   ushort* __restrict__ Sca)
{
    const int bh = blockIdx.x;
    const int hsel = bh & 3;
    const int i = threadIdx.x;
    __shared__ float Ss[64][65];
    const float sT = 0.125f * temp[hsel];

    float m = -1e30f;
    for (int j = 0; j < 64; ++j) {
        float v = 0.f;
        #pragma unroll
        for (int cc = 0; cc < 8; ++cc)
            v += part[((size_t)bh * 8 + cc) * 4096 + i * 64 + j];
        v *= sT;
        Ss[i][j] = v;
        m = fmaxf(m, v);
    }
    float sum = 0.f;
    for (int j = 0; j < 64; ++j) {
        float p = __expf(Ss[i][j] - m);
        Ss[i][j] = p;
        sum += p;
    }
    const float inv = 1.0f / sum;
    for (int j = 0; j < 64; ++j)
        Sca[((size_t)bh << 12) + i * 64 + j] = f2bf(Ss[i][j] * inv);
}

// ---------------------------------------------------------------------------
// Channel stage 3 via MFMA — unchanged from round 3.
// ---------------------------------------------------------------------------
__global__ __launch_bounds__(256) void chan_pv_mfma(const ushort* __restrict__ Sca,
                                                    const ushort* __restrict__ Pvc,
                                                    float* __restrict__ out)
{
    const int nc = blockIdx.x, hh = blockIdx.y, b = blockIdx.z;
    const int t = threadIdx.x;
    const int w = t >> 6, l = t & 63, c = l & 15, g = l >> 4;

    const ushort* S = Sca + ((size_t)(b * 4 + hh) << 12);
    const ushort* V = Pvc + (size_t)b * PROJ_EL + (size_t)hh * HEAD_EL;
    const int n0w = nc * 256 + w * 64;

    f32x4 acc[4][4] = {};
    #pragma unroll
    for (int ks = 0; ks < 2; ++ks) {
        short8_t af[4], bfr[4];
        #pragma unroll
        for (int rt = 0; rt < 4; ++rt)
            af[rt] = *(const short8_t*)&S[(size_t)(rt * 16 + c) * 64 + ks * 32 + 8 * g];
        #pragma unroll
        for (int ct = 0; ct < 4; ++ct)
            bfr[ct] = *(const short8_t*)&V[(size_t)(n0w + ct * 16 + c) * 64 + ks * 32 + 8 * g];
        #pragma unroll
        for (int rt = 0; rt < 4; ++rt)
            #pragma unroll
            for (int ct = 0; ct < 4; ++ct)
                acc[rt][ct] = __builtin_amdgcn_mfma_f32_16x16x32_bf16(
                    af[rt], bfr[ct], acc[rt][ct], 0, 0, 0);
    }

    float* ob = out + (size_t)b * (Nn * 320);
    #pragma unroll
    for (int rt = 0; rt < 4; ++rt)
        #pragma unroll
        for (int ct = 0; ct < 4; ++ct)
            #pragma unroll
            for (int r = 0; r < 4; ++r) {
                int i = rt * 16 + 4 * g + r;
                int nn = n0w + ct * 16 + c;
                int rem = hh * 131072 + i * 2048 + nn;
                ob[(rem >> 8) * 320 + (rem & 255)] = acc[rt][ct][r];
            }
}

// ---------------------------------------------------------------------------
// Spatial attention. 8 waves/block, 16 q-rows per wave, 128 q/block.
// grid (16, H, B) = 256 blocks. No barriers; only P goes through LDS.
// Swapped QK^T: st = mfma(K_frag, Q_frag) -> lane (c,g) holds
// S[q=c][k = tc*16+4g+r] — softmax row is lane-local; row-sum deferred to
// 2 shuffles at the end. No max-subtraction: |scaled logit| < ~0.1.
// PV: oacc = mfma(Vt_frag, P_frag) -> lane holds O[q=c][d=4g+r].
// ---------------------------------------------------------------------------
__global__ __launch_bounds__(512) void spatial_attn2(
    const ushort* __restrict__ Pqs, const ushort* __restrict__ Pks,
    const ushort* __restrict__ PvsT, const float* __restrict__ temp2,
    float* __restrict__ out)
{
    const int qt = blockIdx.x, hh = blockIdx.y, b = blockIdx.z;
    const int t = threadIdx.x, w = t >> 6, l = t & 63;
    const int c = l & 15, g = l >> 4;

    __shared__ ushort P_lds[8][16][72];   // per-wave 16x64 P tile (pad 72)

    const ushort* Qh = Pqs + (size_t)b * PROJ_EL + (size_t)hh * HEAD_EL;
    const ushort* Kh = Pks + (size_t)b * PROJ_EL + (size_t)hh * HEAD_EL;
    const ushort* Vt = PvsT + (size_t)((b * 4 + hh) * 16) * 2048;   // (16, 2048)
    const float sT2 = 0.125f * temp2[hh] * 1.44269504f;   // fold log2(e)

    const int q0 = qt * 128 + w * 16;
    const ushort* qp = Qh + (size_t)(q0 + c) * 64 + 8 * g;
    const short8_t qf0 = *(const short8_t*)qp;
    const short8_t qf1 = *(const short8_t*)(qp + 32);

    f32x4 oacc = {0.f, 0.f, 0.f, 0.f};
    float lsum = 0.f;
    ushort* Pw = &P_lds[w][0][0];         // row stride 72 ushorts

    for (int kc = 0; kc < 32; ++kc) {
        const int kb = kc * 64;
        // S^T row-tiles: A = K rows (global, L2-hot), B = Q regs
        #pragma unroll
        for (int tc = 0; tc < 4; ++tc) {
            const ushort* kp = Kh + (size_t)(kb + tc * 16 + c) * 64 + 8 * g;
            short8_t kf0 = *(const short8_t*)kp;
            short8_t kf1 = *(const short8_t*)(kp + 32);
            f32x4 st = {0.f, 0.f, 0.f, 0.f};
            st = __builtin_amdgcn_mfma_f32_16x16x32_bf16(kf0, qf0, st, 0, 0, 0);
            st = __builtin_amdgcn_mfma_f32_16x16x32_bf16(kf1, qf1, st, 0, 0, 0);
            float p0 = __builtin_amdgcn_exp2f(st[0] * sT2);
            float p1 = __builtin_amdgcn_exp2f(st[1] * sT2);
            float p2 = __builtin_amdgcn_exp2f(st[2] * sT2);
            float p3 = __builtin_amdgcn_exp2f(st[3] * sT2);
            lsum += (p0 + p1) + (p2 + p3);
            unsigned u01, u23;
            asm("v_cvt_pk_bf16_f32 %0, %1, %2" : "=v"(u01) : "v"(p0), "v"(p1));
            asm("v_cvt_pk_bf16_f32 %0, %1, %2" : "=v"(u23) : "v"(p2), "v"(p3));
            *(unsigned*)&Pw[(size_t)c * 72 + tc * 16 + 4 * g]     = u01;
            *(unsigned*)&Pw[(size_t)c * 72 + tc * 16 + 4 * g + 2] = u23;
        }
        // O^T += V^T * P^T : A = V^T rows d (global), B = P rows q (LDS)
        #pragma unroll
        for (int ks = 0; ks < 2; ++ks) {
            short8_t vf = *(const short8_t*)&Vt[(size_t)c * 2048 + kb + ks * 32 + 8 * g];
            short8_t pf = *(const short8_t*)&Pw[(size_t)c * 72 + ks * 32 + 8 * g];
            oacc = __builtin_amdgcn_mfma_f32_16x16x32_bf16(vf, pf, oacc, 0, 0, 0);
        }
    }

    // full row-sum for q = c: reduce across the 4 lane-groups holding it
    lsum += __shfl_xor(lsum, 16);
    lsum += __shfl_xor(lsum, 32);
    const float inv = 1.0f / lsum;

    // raw-reshape scatter: nn = q-row; row n, cols 256+(nn&3)*16+4g..+3
    const int nn = q0 + c;
    const int n = hh * 512 + (nn >> 2);
    const int cc = 256 + ((nn & 3) << 4) + 4 * g;
    float4 o4 = make_float4(oacc[0] * inv, oacc[1] * inv, oacc[2] * inv, oacc[3] * inv);
    *(float4*)&out[((size_t)b * Nn + n) * 320 + cc] = o4;
}

// ---------------------------------------------------------------------------
extern "C" void kernel_launch(void* const* d_in, const int* in_sizes, int n_in,
                              void* d_out, int out_size, void* d_ws, size_t ws_size,
                              hipStream_t stream)
{
    const float* s     = (const float*)d_in[0];
    const float* h     = (const float*)d_in[1];
    const float* sh    = (const float*)d_in[2];
    const float* temp  = (const float*)d_in[3];
    const float* temp2 = (const float*)d_in[4];
    const float* Wq_c  = (const float*)d_in[5];
    const float* Wq_s  = (const float*)d_in[6];
    const float* Wk_c  = (const float*)d_in[7];
    const float* Wv_c  = (const float*)d_in[8];
    const float* Wk_s  = (const float*)d_in[9];
    const float* Wv_s  = (const float*)d_in[10];
    float* out = (float*)d_out;
    float* ws = (float*)d_ws;

    ushort* sb    = (ushort*)(ws + OFF_SB);
    ushort* shb   = (ushort*)(ws + OFF_SHB);
    ushort* hb    = (ushort*)(ws + OFF_HB);
    ushort* wqcb  = (ushort*)(ws + OFF_WQC);
    ushort* wcatb = (ushort*)(ws + OFF_WCAT);
    ushort* wvsb  = (ushort*)(ws + OFF_WVS);
    ushort* Pqc   = (ushort*)(ws + OFF_PQC);
    ushort* Pqs   = (ushort*)(ws + OFF_PQS);
    ushort* Pkc   = (ushort*)(ws + OFF_PKC);
    ushort* Pvc   = (ushort*)(ws + OFF_PVC);
    ushort* Pks   = (ushort*)(ws + OFF_PKS);
    ushort* PvsT  = (ushort*)(ws + OFF_PVST);
    float*  part  = ws + OFF_PART;
    ushort* Sca   = (ushort*)(ws + OFF_SCA);

    const dim3 blk(256);

    // 1) f32 -> bf16 conversions
    convert_all<<<dim3((SEG8 / 8 + 255) / 256), blk, 0, stream>>>(
        s, sh, h, Wq_c, Wq_s, Wk_c, Wv_c, Wk_s, Wv_s,
        sb, shb, hb, wqcb, wcatb, wvsb);

    // 2) projections
    mfma_gemm<<<dim3(8, 64), blk, 0, stream>>>(shb, wcatb, Pqs, Pkc, Pvc, Pks, 256);
    mfma_gemm<<<dim3(2, 64), blk, 0, stream>>>(sb, wqcb, Pqc, Pqc, Pqc, Pqc, 256);
    mfma_gemm_vs<<<dim3(32), blk, 0, stream>>>(wvsb, hb, PvsT);

    // 3) channel branch
    chan_qk_partial<<<dim3(8, 4, 4), blk, 0, stream>>>(Pqc, Pkc, part);
    chan_softmax<<<dim3(16), dim3(64), 0, stream>>>(part, temp, Sca);
    chan_pv_mfma<<<dim3(8, 4, 4), blk, 0, stream>>>(Sca, Pvc, out);

    // 4) spatial branch (no barriers, 8 waves/block)
    spatial_attn2<<<dim3(16, 4, 4), dim3(512), 0, stream>>>(Pqs, Pks, PvsT, temp2, out);
}